// Round 9
// baseline (16.935 us; speedup 1.0000x reference)
//
#include <hip/hip_runtime.h>
#include <hip/hip_bf16.h>
#include <math.h>

// Fused MFMA chamfer. S[target r][pred c] = 0.5*t^2 - p.t via ONE
// v_mfma_f32_32x32x16_bf16 per 32x32 tile, hi/lo bf16 K-packing (R7-validated):
//   A row r (target): k0-2=th, k3-5=th, k6-7=tl.xy | k8=tl.z, k9=qh, k10=ql
//   B col c (pred)  : k0-2=-ph, k3-5=-pl, k6-7=-ph.xy | k8=-ph.z, k9=1, k10=1
// dot = 0.5*t^2 - p.t + O(1e-4);  d^2/2 = dot + 0.5*p^2 (added in epilogue).
// Block = (batch, 128-pred panel): grid 256 = 1 block/CU. All 2048 targets
// staged once in 64 KB LDS; each wave owns one 32-pred tile and loops all 64
// target tiles, cross-tile min in registers (no minS buffer, no merge kernel).
// Epilogue in-wave: min-tree + shfl_xor(32), +0.5p^2, sqrt, asym, blend;
// per-wave partial -> d_ws (plain store). 1-block reducer sums 1024 partials
// in fixed order -> deterministic, no atomics, no memset.

typedef short short8 __attribute__((ext_vector_type(8)));
typedef float f32x16 __attribute__((ext_vector_type(16)));

__device__ __forceinline__ unsigned short f2bf(float f) {  // RNE f32->bf16
  unsigned u = __float_as_uint(f);
  u = u + 0x7FFFu + ((u >> 16) & 1u);
  return (unsigned short)(u >> 16);
}
__device__ __forceinline__ float bf2f(unsigned short h) {
  return __uint_as_float(((unsigned)h) << 16);
}

#define TPB 256
#define NPTS 2048  // N (kernel sized for the fixed problem shape)

__global__ __launch_bounds__(TPB) void chamfer_fused_mfma_kernel(
    const float* __restrict__ pred, const float* __restrict__ targ,
    const float* __restrict__ sym_flag, float* __restrict__ partial,
    int N, int B, int panelsPerBatch) {
  __shared__ short8 sA[2][NPTS];  // 64 KB: packed A fragments, both K-halves

  const int blk = blockIdx.x;
  const int pp = blk % panelsPerBatch;  // pred panel (16 per batch)
  const int b = blk / panelsPerBatch;

  // ---- stage + convert ALL targets of this batch (8 per thread)
  const float* tb = targ + (size_t)b * N * 3;
  for (int t = threadIdx.x; t < N; t += TPB) {
    const float x = tb[t * 3], y = tb[t * 3 + 1], z = tb[t * 3 + 2];
    const unsigned short thx = f2bf(x), thy = f2bf(y), thz = f2bf(z);
    const unsigned short tlx = f2bf(x - bf2f(thx));
    const unsigned short tly = f2bf(y - bf2f(thy));
    const unsigned short tlz = f2bf(z - bf2f(thz));
    const float q = 0.5f * (x * x + y * y + z * z);
    const unsigned short qh = f2bf(q), ql = f2bf(q - bf2f(qh));
    sA[0][t] = short8{(short)thx, (short)thy, (short)thz, (short)thx,
                      (short)thy, (short)thz, (short)tlx, (short)tly};
    sA[1][t] = short8{(short)tlz, (short)qh, (short)ql, 0, 0, 0, 0, 0};
  }

  const int lane = threadIdx.x & 63;
  const int w = threadIdx.x >> 6;
  const int g = lane >> 5;   // which K-half this lane holds
  const int l31 = lane & 31;
  const int col = pp * 128 + w * 32 + l31;  // this lane's pred column

  // ---- B fragment for this lane's pred col (negated hi/lo split)
  const float* pq = pred + ((size_t)b * N + col) * 3;
  const float px = pq[0], py = pq[1], pz = pq[2];
  short8 bfr;
  {
    const unsigned short hx = f2bf(-px), hy = f2bf(-py), hz = f2bf(-pz);
    const unsigned short lx = f2bf(-px - bf2f(hx));
    const unsigned short ly = f2bf(-py - bf2f(hy));
    const unsigned short lz = f2bf(-pz - bf2f(hz));
    if (g == 0)
      bfr = short8{(short)hx, (short)hy, (short)hz, (short)lx,
                   (short)ly, (short)lz, (short)hx, (short)hy};
    else
      bfr = short8{(short)hz, (short)0x3F80, (short)0x3F80, 0, 0, 0, 0, 0};
  }
  __syncthreads();

  const f32x16 zc = {0.f, 0.f, 0.f, 0.f, 0.f, 0.f, 0.f, 0.f,
                     0.f, 0.f, 0.f, 0.f, 0.f, 0.f, 0.f, 0.f};
  float rm[8];
#pragma unroll
  for (int i = 0; i < 8; ++i) rm[i] = 3.4e38f;

  // ---- main loop: all 64 target tiles; 1 ds_read_b128 + 1 MFMA + 8 min3
#pragma unroll 4
  for (int ta = 0; ta < NPTS / 32; ++ta) {
    const short8 a = sA[g][ta * 32 + l31];
    const f32x16 d = __builtin_amdgcn_mfma_f32_32x32x16_bf16(a, bfr, zc, 0, 0, 0);
#pragma unroll
    for (int i = 0; i < 8; ++i)
      rm[i] = fminf(rm[i], fminf(d[2 * i], d[2 * i + 1]));  // v_min3
  }

  // ---- per-col min over ALL targets (in-lane tree + cross-half merge)
  float m = rm[0];
#pragma unroll
  for (int i = 1; i < 8; ++i) m = fminf(m, rm[i]);
  m = fminf(m, __shfl_xor(m, 32));

  // ---- epilogue: recover distance, asym term, blend (lanes 0..31 live)
  const float hp2 = 0.5f * (px * px + py * py + pz * pz);
  const float dsym = sqrtf(fmaxf(2.f * (m + hp2), 1e-12f));
  const float* tq = targ + ((size_t)b * N + col) * 3;
  const float dx = px - tq[0], dy = py - tq[1], dz = pz - tq[2];
  const float dasym = sqrtf(dx * dx + dy * dy + dz * dz);
  const float f = sym_flag[b];
  float c = (lane < 32) ? (f * dsym + (1.f - f) * dasym) : 0.f;
#pragma unroll
  for (int off = 32; off > 0; off >>= 1) c += __shfl_xor(c, off);
  if (lane == 0) partial[blk * 4 + w] = c;  // plain store, deterministic
}

// Reducer: one block, fixed-order sum of 1024 per-wave partials.
__global__ __launch_bounds__(256) void chamfer_sum_kernel(
    const float* __restrict__ partial, float* __restrict__ out,
    int nPartial, float invNB) {
  const float4 v = ((const float4*)partial)[threadIdx.x];  // 4 per thread
  float s = (v.x + v.y) + (v.z + v.w);
#pragma unroll
  for (int off = 32; off > 0; off >>= 1) s += __shfl_xor(s, off);
  __shared__ float sW[4];
  if ((threadIdx.x & 63) == 0) sW[threadIdx.x >> 6] = s;
  __syncthreads();
  if (threadIdx.x == 0)
    out[0] = (sW[0] + sW[1] + sW[2] + sW[3]) * invNB;
}

extern "C" void kernel_launch(void* const* d_in, const int* in_sizes, int n_in,
                              void* d_out, int out_size, void* d_ws, size_t ws_size,
                              hipStream_t stream) {
  const float* pred = (const float*)d_in[0];
  const float* targ = (const float*)d_in[1];
  const float* sym_flag = (const float*)d_in[2];
  float* out = (float*)d_out;

  const int B = in_sizes[2];            // 16
  const int N = in_sizes[0] / (B * 3);  // 2048 (NPTS)

  const int panelsPerBatch = N / 128;   // 16
  const int grid1 = B * panelsPerBatch; // 256 blocks = 1 per CU
  float* partial = (float*)d_ws;        // grid1*4 floats (per-wave partials)

  chamfer_fused_mfma_kernel<<<grid1, TPB, 0, stream>>>(
      pred, targ, sym_flag, partial, N, B, panelsPerBatch);

  chamfer_sum_kernel<<<1, 256, 0, stream>>>(
      partial, out, grid1 * 4, 1.0f / (float)(N * B));
}